// Round 4
// baseline (194.755 us; speedup 1.0000x reference)
//
#include <hip/hip_runtime.h>

// ConnectLoss fused kernel v4 for MI355X (gfx950).
//
// v3 post-mortem: vmem-issue theory was off by 64x (thread vs wave instrs);
// main kernel is ~15 us (HBM compulsory 73 MB ~= 12 us floor) and dur_us is
// dominated by harness graph ops (256 MiB d_ws poison = 41 us + restores).
// v4 squeezes the controllable part: waves share sigmoid values via LDS
// (eliminates duplicate neighbor-row loads + 64 fast_sig/thread), and the
// finalize is fused into the main kernel via last-block atomic counter
// (removes one kernel node + gap).

#define HDIM 512
#define WDIM 512
#define HW (HDIM * WDIM)
#define BATCH 8
#define RPB 4                      // rows per block; wave == one row
#define NBLKX (HDIM / RPB)         // 128 blocks per image
#define NBLK  (NBLKX * BATCH)      // 1024 blocks

__device__ __forceinline__ float fast_sig(float x) {
    float e = __expf(-fabsf(x));
    float r = __builtin_amdgcn_rcpf(1.0f + e);
    return (x >= 0.0f) ? r : e * r;
}
// sigmoid(x); sp_out = log(1+exp(-|x|)) so softplus(+-x) = max(+-x,0)+sp_out
__device__ __forceinline__ float sig_sp(float x, float& sp_out) {
    float e = __expf(-fabsf(x));
    float d = 1.0f + e;
    sp_out = __logf(d);
    float r = __builtin_amdgcn_rcpf(d);
    return (x >= 0.0f) ? r : e * r;
}

struct Arr10 { float v[10]; };     // cols j0-1 .. j0+8

__device__ __forceinline__ void load8(const float* p, float* o) {
    const float4 a = *(const float4*)p;
    const float4 b = *(const float4*)(p + 4);
    o[0]=a.x; o[1]=a.y; o[2]=a.z; o[3]=a.w;
    o[4]=b.x; o[5]=b.y; o[6]=b.z; o[7]=b.w;
}
__device__ __forceinline__ void store8(float* p, const float* v) {
    *(float4*)p       = make_float4(v[0], v[1], v[2], v[3]);
    *(float4*)(p + 4) = make_float4(v[4], v[5], v[6], v[7]);
}

// build 10-col strip; lane-0 left / lane-63 right are image boundary -> 0
__device__ __forceinline__ Arr10 strip10_from(const float* x, int lane) {
    Arr10 r;
    float l = __shfl_up(x[7], 1, 64);
    float h = __shfl_down(x[0], 1, 64);
    r.v[0] = (lane == 0)  ? 0.f : l;
    r.v[9] = (lane == 63) ? 0.f : h;
#pragma unroll
    for (int k = 0; k < 8; ++k) r.v[k + 1] = x[k];
    return r;
}
__device__ __forceinline__ Arr10 strip_lds(const float* rowp, int j0, int lane) {
    float x[8];
    load8(rowp + j0, x);           // ds_read_b128 x2, conflict-free
    return strip10_from(x, lane);
}
__device__ __forceinline__ Arr10 load_strip10(const float* p, int lane, bool valid) {
    float x[8] = {0.f,0.f,0.f,0.f,0.f,0.f,0.f,0.f};
    if (valid) load8(p, x);        // valid is wave-uniform
    return strip10_from(x, lane);
}

__global__ __launch_bounds__(256) void connect_loss_main(
        const float* __restrict__ pred,   // (B, 8, H, W)
        const float* __restrict__ tgt,    // (B, 1, H, W)
        float* __restrict__ partials,     // mode 1: [6][NBLK]
        unsigned int* __restrict__ counter,
        double* __restrict__ wsd,         // mode 0: 27 doubles
        float* __restrict__ out,
        int mode)
{
    __shared__ __align__(16) float ldsA[3][RPB][WDIM]; // ch 5,6,7 rows r-1..r+2
    __shared__ __align__(16) float ldsB[3][RPB][WDIM]; // ch 0,1,2 rows r+1..r+4
    __shared__ float red[4][6];

    const int b    = blockIdx.y;
    const int tid  = threadIdx.x;
    const int lane = tid & 63;
    const int wv   = tid >> 6;
    const int r    = blockIdx.x * RPB;
    const int i    = r + wv;                 // wave == one row
    const int j0   = lane << 3;
    const int p0   = i * WDIM + j0;
    const bool rm  = (i > 0), rp = (i < HDIM - 1);

    const float* tb = tgt  + (size_t)b * HW;
    const float* pb = pred + (size_t)b * 8 * HW;

    // ---------- target rows i-1, i, i+1: conn bits + edge + target bit ----
    Arr10 nm = load_strip10(tb + (rm ? p0 - WDIM : p0), lane, rm);
    Arr10 nc = load_strip10(tb + p0,                    lane, true);
    Arr10 np = load_strip10(tb + (rp ? p0 + WDIM : p0), lane, rp);

    int mb[8];
#pragma unroll
    for (int k = 0; k < 8; ++k) {
        const float t_ = nc.v[k + 1];
        const float s8 = nm.v[k] + nm.v[k+1] + nm.v[k+2]
                       + nc.v[k] + nc.v[k+2]
                       + np.v[k] + np.v[k+1] + np.v[k+2];
        const float sc = t_ * s8;
        int bits = (sc < 8.0f && sc > 0.0f) ? 256 : 0;
        if (t_ > 0.5f) {
            bits |= 512;
            bits |= (nm.v[k]   > 0.5f ?   1 : 0);
            bits |= (nm.v[k+1] > 0.5f ?   2 : 0);
            bits |= (nm.v[k+2] > 0.5f ?   4 : 0);
            bits |= (nc.v[k]   > 0.5f ?   8 : 0);
            bits |= (nc.v[k+2] > 0.5f ?  16 : 0);
            bits |= (np.v[k]   > 0.5f ?  32 : 0);
            bits |= (np.v[k+1] > 0.5f ?  64 : 0);
            bits |= (np.v[k+2] > 0.5f ? 128 : 0);
        }
        mb[k] = bits;
    }

    // ---------- own-pixel channels: sigmoid + BCE + xmin ----------
    float s[8][8], xmin[8], fp[8];
#pragma unroll
    for (int k = 0; k < 8; ++k) { xmin[k] = 1e30f; fp[k] = 0.f; }
    float bce = 0.f;
#pragma unroll
    for (int c = 0; c < 8; ++c) {
        float x[8];
        load8(pb + (size_t)c * HW + p0, x);
#pragma unroll
        for (int k = 0; k < 8; ++k) {
            float sp;
            const float sv = sig_sp(x[k], sp);
            s[c][k] = sv;
            xmin[k] = fminf(xmin[k], x[k]);
            const float sp_pos = fmaxf( x[k], 0.f) + sp;  // softplus(x)
            const float sp_neg = fmaxf(-x[k], 0.f) + sp;  // softplus(-x)
            bce += ((mb[k] >> c) & 1) ? fminf(sp_neg, 100.f)
                                      : fminf(sp_pos, 100.f);
        }
    }

    // ---------- publish shared sigmoid rows ----------
    if (wv < 3) {
#pragma unroll
        for (int c = 5; c <= 7; ++c) store8(&ldsA[c - 5][wv + 1][j0], s[c]);
    }
    if (wv > 0) {
#pragma unroll
        for (int c = 0; c <= 2; ++c) store8(&ldsB[c][wv - 1][j0], s[c]);
    }
    if (wv == 0 && blockIdx.x > 0) {            // halo row r-1, ch 5..7
        const int q0 = p0 - WDIM;
#pragma unroll
        for (int c = 5; c <= 7; ++c) {
            float x[8], v[8];
            load8(pb + (size_t)c * HW + q0, x);
#pragma unroll
            for (int k = 0; k < 8; ++k) v[k] = fast_sig(x[k]);
            store8(&ldsA[c - 5][0][j0], v);
        }
    }
    if (wv == 3 && blockIdx.x < NBLKX - 1) {    // halo row r+4, ch 0..2
        const int q0 = p0 + WDIM;
#pragma unroll
        for (int c = 0; c <= 2; ++c) {
            float x[8], v[8];
            load8(pb + (size_t)c * HW + q0, x);
#pragma unroll
            for (int k = 0; k < 8; ++k) v[k] = fast_sig(x[k]);
            store8(&ldsB[c][3][j0], v);
        }
    }

    // ---------- in-row votes (regs only, before barrier) ----------
    {
        Arr10 n4 = strip10_from(s[4], lane);    // values of ch4, cols j-1..j+8
        Arr10 n3 = strip10_from(s[3], lane);
#pragma unroll
        for (int k = 0; k < 8; ++k) {
            fp[k] = fmaxf(fp[k], s[3][k] * n4.v[k]);       // d3: ch4@(i,j-1)
            fp[k] = fmaxf(fp[k], s[4][k] * n3.v[k + 2]);   // d4: ch3@(i,j+1)
        }
    }

    __syncthreads();

    // ---------- cross-row votes from LDS (wave-uniform predicates) ----------
    if (rm) {
        Arr10 n7 = strip_lds(&ldsA[2][wv][0], j0, lane);
        Arr10 n6 = strip_lds(&ldsA[1][wv][0], j0, lane);
        Arr10 n5 = strip_lds(&ldsA[0][wv][0], j0, lane);
#pragma unroll
        for (int k = 0; k < 8; ++k) {
            fp[k] = fmaxf(fp[k], s[0][k] * n7.v[k]);       // d0: ch7@(i-1,j-1)
            fp[k] = fmaxf(fp[k], s[1][k] * n6.v[k + 1]);   // d1: ch6@(i-1,j)
            fp[k] = fmaxf(fp[k], s[2][k] * n5.v[k + 2]);   // d2: ch5@(i-1,j+1)
        }
    }
    if (rp) {
        Arr10 n2 = strip_lds(&ldsB[2][wv][0], j0, lane);
        Arr10 n1 = strip_lds(&ldsB[1][wv][0], j0, lane);
        Arr10 n0 = strip_lds(&ldsB[0][wv][0], j0, lane);
#pragma unroll
        for (int k = 0; k < 8; ++k) {
            fp[k] = fmaxf(fp[k], s[5][k] * n2.v[k]);       // d5: ch2@(i+1,j-1)
            fp[k] = fmaxf(fp[k], s[6][k] * n1.v[k + 1]);   // d6: ch1@(i+1,j)
            fp[k] = fmaxf(fp[k], s[7][k] * n0.v[k + 2]);   // d7: ch0@(i+1,j+1)
        }
    }

    // ---------- epilogue: edge loss + dice partials ----------
    float e_num = 0.f, e_den = 0.f, inter = 0.f, fpsum = 0.f, tsum = 0.f;
#pragma unroll
    for (int k = 0; k < 8; ++k) {
        const float ef  = (mb[k] & 256) ? 1.f : 0.f;
        const float tkf = (mb[k] & 512) ? 1.f : 0.f;
        const float m   = xmin[k];
        float sp;
        const float pmin = sig_sp(m, sp);                  // sigmoid monotone
        e_num += ef * fminf(fmaxf(m, 0.f) + sp, 100.f);    // softplus(xmin)
        e_den += ef * pmin;
        inter += fp[k] * tkf;
        fpsum += fp[k];
        tsum  += tkf;
    }

    // ---------- block reduction of 6 partials ----------
    float vals[6] = {bce, e_num, e_den, inter, fpsum, tsum};
#pragma unroll
    for (int k = 0; k < 6; ++k) {
        float v = vals[k];
#pragma unroll
        for (int o = 32; o > 0; o >>= 1) v += __shfl_down(v, o, 64);
        if (lane == 0) red[wv][k] = v;
    }
    __syncthreads();

    if (mode == 0) {
        if (tid < 6) {
            const int k = tid;
            const float sum = red[0][k] + red[1][k] + red[2][k] + red[3][k];
            double* dst;
            switch (k) {
                case 0:  dst = wsd + 0;       break;
                case 1:  dst = wsd + 1;       break;
                case 2:  dst = wsd + 2;       break;
                case 3:  dst = wsd + 3 + b;   break;
                case 4:  dst = wsd + 11 + b;  break;
                default: dst = wsd + 19 + b;  break;
            }
            atomicAdd(dst, (double)sum);
        }
        return;
    }

    // ---------- mode 1: publish partials, last block finalizes ----------
    if (tid < 6) {
        const int k = tid;
        const float sum = red[0][k] + red[1][k] + red[2][k] + red[3][k];
        partials[k * NBLK + b * NBLKX + blockIdx.x] = sum;
    }
    __threadfence();
    __shared__ unsigned int done_flag;
    if (tid == 0) done_flag = atomicAdd(counter, 1u);
    __syncthreads();
    if (done_flag != NBLK - 1) return;
    __threadfence();   // acquire: make all blocks' partials visible

    __shared__ double red4[4];
    __shared__ double gsum[3];
    __shared__ double bsum[3][BATCH];
    {   // per-batch categories (k=3,4,5): 8 groups of 32 lanes
        const int g = tid >> 5, e = tid & 31;
#pragma unroll
        for (int k = 3; k < 6; ++k) {
            double v = 0.0;
            for (int m = e; m < NBLKX; m += 32)
                v += (double)partials[k * NBLK + g * NBLKX + m];
            for (int o = 16; o > 0; o >>= 1) v += __shfl_down(v, o, 32);
            if (e == 0) bsum[k - 3][g] = v;
        }
    }
    for (int k = 0; k < 3; ++k) {               // global categories
        double v = 0.0;
        for (int idx = tid; idx < NBLK; idx += 256)
            v += (double)partials[k * NBLK + idx];
        for (int o = 32; o > 0; o >>= 1) v += __shfl_down(v, o, 64);
        if (lane == 0) red4[wv] = v;
        __syncthreads();
        if (tid == 0) gsum[k] = red4[0] + red4[1] + red4[2] + red4[3];
        __syncthreads();
    }
    if (tid == 0) {
        const double conn_loss = gsum[0] / (double)((size_t)BATCH * 8 * HW);
        const double edge_loss = gsum[1] / gsum[2];
        double seg = 0.0;
        for (int bb = 0; bb < BATCH; ++bb) {
            const double dice = (2.0 * bsum[0][bb] + 1.0)
                              / (bsum[1][bb] + bsum[2][bb] + 1.0);
            seg += 1.0 - dice;
        }
        out[0] = (float)(conn_loss + edge_loss + seg / (double)BATCH);
    }
}

__global__ void connect_loss_final0(const double* __restrict__ wsd,
                                    float* __restrict__ out)
{
    const double conn_loss = wsd[0] / (double)((size_t)BATCH * 8 * HW);
    const double edge_loss = wsd[1] / wsd[2];
    double seg = 0.0;
    for (int bb = 0; bb < BATCH; ++bb) {
        const double dice = (2.0 * wsd[3 + bb] + 1.0)
                          / (wsd[11 + bb] + wsd[19 + bb] + 1.0);
        seg += 1.0 - dice;
    }
    out[0] = (float)(conn_loss + edge_loss + seg / (double)BATCH);
}

extern "C" void kernel_launch(void* const* d_in, const int* in_sizes, int n_in,
                              void* d_out, int out_size, void* d_ws, size_t ws_size,
                              hipStream_t stream)
{
    const float* pred = (const float*)d_in[0];   // (8, 8, 512, 512)
    const float* tgt  = (const float*)d_in[1];   // (8, 1, 512, 512)
    // d_in[2]/d_in[3] (hori/verti) are exact one-pixel shift permutation
    // matrices -> implemented as index shifts (verified rounds 1-3, absmax 0).

    const dim3 grid(NBLKX, BATCH);
    const size_t needA = 16 + (size_t)6 * NBLK * sizeof(float);

    if (ws_size >= needA) {
        unsigned int* counter = (unsigned int*)d_ws;
        float* partials = (float*)((char*)d_ws + 16);
        hipMemsetAsync(d_ws, 0, 16, stream);     // zero the arrival counter
        connect_loss_main<<<grid, 256, 0, stream>>>(
            pred, tgt, partials, counter, nullptr, (float*)d_out, 1);
    } else {
        double* wsd = (double*)d_ws;
        hipMemsetAsync(d_ws, 0, 27 * sizeof(double), stream);
        connect_loss_main<<<grid, 256, 0, stream>>>(
            pred, tgt, nullptr, nullptr, wsd, (float*)d_out, 0);
        connect_loss_final0<<<1, 1, 0, stream>>>(wsd, (float*)d_out);
    }
}

// Round 5
// 134.572 us; speedup vs baseline: 1.4472x; 1.4472x over previous
//
#include <hip/hip_runtime.h>

// ConnectLoss fused kernel v5 for MI355X (gfx950).
//
// v4 post-mortem: per-block device-scope __threadfence (executed by all
// threads) + 48.5 KB LDS occupancy cliff + mid-kernel barrier made main
// 110 us @ 16% VALUBusy -> reverted to v3 structure (134.3 us, absmax 0).
// v5 = v3 + in-row votes (pair 3,4) use wave-shuffled sigmoid VALUES
// (no re-fast_sig of shuffled logits; boundary zeros = OOB semantics).

#define HDIM 512
#define WDIM 512
#define HW (HDIM * WDIM)
#define BATCH 8
#define ROWS_PER_BLOCK 4
#define NBLKX (HDIM / ROWS_PER_BLOCK)   // 128 blocks per batch image
#define NBLK  (NBLKX * BATCH)           // 1024 blocks total

__device__ __forceinline__ float fast_sig(float x) {
    float e = __expf(-fabsf(x));
    float r = __builtin_amdgcn_rcpf(1.0f + e);
    return (x >= 0.0f) ? r : e * r;
}
// sigmoid(x); sp_out = log(1+exp(-|x|)) so softplus(+-x) = max(+-x,0) + sp_out
__device__ __forceinline__ float sig_sp(float x, float& sp_out) {
    float e = __expf(-fabsf(x));
    float d = 1.0f + e;
    sp_out = __logf(d);
    float r = __builtin_amdgcn_rcpf(d);
    return (x >= 0.0f) ? r : e * r;
}

struct Arr10 { float v[10]; };  // cols j0-1 .. j0+8 (halos via wave shuffle)

__device__ __forceinline__ void load8(const float* p, float* o) {
    const float4 a = *(const float4*)p;
    const float4 b = *(const float4*)(p + 4);
    o[0]=a.x; o[1]=a.y; o[2]=a.z; o[3]=a.w;
    o[4]=b.x; o[5]=b.y; o[6]=b.z; o[7]=b.w;
}

__device__ __forceinline__ Arr10 strip10_from(const float* x, int lane) {
    Arr10 r;
    float l = __shfl_up(x[7], 1, 64);
    float h = __shfl_down(x[0], 1, 64);
    r.v[0] = (lane == 0)  ? 0.f : l;    // image-left boundary
    r.v[9] = (lane == 63) ? 0.f : h;    // image-right boundary
#pragma unroll
    for (int k = 0; k < 8; ++k) r.v[k + 1] = x[k];
    return r;
}

__device__ __forceinline__ Arr10 load_strip10(const float* p, int lane, bool valid) {
    float x[8] = {0.f,0.f,0.f,0.f,0.f,0.f,0.f,0.f};
    if (valid) load8(p, x);             // valid is wave-uniform
    return strip10_from(x, lane);
}

__global__ __launch_bounds__(256) void connect_loss_main(
        const float* __restrict__ pred,   // (B, 8, H, W)
        const float* __restrict__ tgt,    // (B, 1, H, W)
        float* __restrict__ partials,     // mode 1: [6][NBLK]
        double* __restrict__ wsd,         // mode 0: 27 doubles
        int mode)
{
    const int b    = blockIdx.y;
    const int tid  = threadIdx.x;
    const int lane = tid & 63;
    const int wv   = tid >> 6;
    const int i    = blockIdx.x * ROWS_PER_BLOCK + wv;  // wave == one row
    const int j0   = lane << 3;
    const int p0   = i * WDIM + j0;
    const bool rm  = (i > 0), rp = (i < HDIM - 1);
    const bool l0  = (lane == 0), l63 = (lane == 63);

    const float* tb = tgt  + (size_t)b * HW;
    const float* pb = pred + (size_t)b * 8 * HW;

    // ---------- target rows i-1, i, i+1 ----------
    Arr10 nm = load_strip10(tb + (rm ? p0 - WDIM : p0), lane, rm);
    Arr10 nc = load_strip10(tb + p0,                    lane, true);
    Arr10 np = load_strip10(tb + (rp ? p0 + WDIM : p0), lane, rp);

    // conn bits (0..7) + edge flag (bit 8) per pixel; tk kept for dice terms
    float tk[8]; int mb[8];
#pragma unroll
    for (int k = 0; k < 8; ++k) {
        const float t_ = nc.v[k + 1];
        tk[k] = t_;
        const float s8 = nm.v[k] + nm.v[k+1] + nm.v[k+2]
                       + nc.v[k] + nc.v[k+2]
                       + np.v[k] + np.v[k+1] + np.v[k+2];
        const float sc = t_ * s8;
        int bits = (sc < 8.0f && sc > 0.0f) ? 256 : 0;
        if (t_ > 0.5f) {
            bits |= (nm.v[k]   > 0.5f ?   1 : 0);
            bits |= (nm.v[k+1] > 0.5f ?   2 : 0);
            bits |= (nm.v[k+2] > 0.5f ?   4 : 0);
            bits |= (nc.v[k]   > 0.5f ?   8 : 0);
            bits |= (nc.v[k+2] > 0.5f ?  16 : 0);
            bits |= (np.v[k]   > 0.5f ?  32 : 0);
            bits |= (np.v[k+1] > 0.5f ?  64 : 0);
            bits |= (np.v[k+2] > 0.5f ? 128 : 0);
        }
        mb[k] = bits;
    }

    float fp[8], xmin[8], bce = 0.f;
#pragma unroll
    for (int k = 0; k < 8; ++k) { fp[k] = 0.f; xmin[k] = 1e30f; }

    // own-channel math: sigmoid + BCE (logit-space softplus) + xmin
    auto own_ch = [&](int c, const float* x, float* s) {
#pragma unroll
        for (int k = 0; k < 8; ++k) {
            float sp;
            const float sv = sig_sp(x[k], sp);
            s[k] = sv;
            xmin[k] = fminf(xmin[k], x[k]);
            const float sp_pos = fmaxf( x[k], 0.f) + sp;  // softplus(x)
            const float sp_neg = fmaxf(-x[k], 0.f) + sp;  // softplus(-x)
            bce += ((mb[k] >> c) & 1) ? fminf(sp_neg, 100.f)
                                      : fminf(sp_pos, 100.f);
        }
    };
    // cross-row vote from LOGIT strips: fp = max(fp, s * sigmoid(neigh))
    auto vote = [&](const float* s, const Arr10& n, int off, bool rv) {
#pragma unroll
        for (int k = 0; k < 8; ++k) {
            bool ok = rv;
            if (off == 0 && k == 0) ok = ok && !l0;
            if (off == 2 && k == 7) ok = ok && !l63;
            const float q = ok ? fast_sig(n.v[k + off]) : 0.f;
            fp[k] = fmaxf(fp[k], s[k] * q);
        }
    };

    float x_a[8], x_b[8], s_a[8], s_b[8];

    // ---- pair (0,7): d0 uses ch7@(i-1,j-1); d7 uses ch0@(i+1,j+1) ----
    load8(pb + 0 * (size_t)HW + p0, x_a);
    load8(pb + 7 * (size_t)HW + p0, x_b);
    {
        Arr10 n7 = load_strip10(pb + 7*(size_t)HW + (rm ? p0 - WDIM : p0), lane, rm);
        Arr10 n0 = load_strip10(pb + 0*(size_t)HW + (rp ? p0 + WDIM : p0), lane, rp);
        own_ch(0, x_a, s_a);
        own_ch(7, x_b, s_b);
        vote(s_a, n7, 0, rm);
        vote(s_b, n0, 2, rp);
    }
    // ---- pair (1,6): d1 uses ch6@(i-1,j); d6 uses ch1@(i+1,j) ----
    load8(pb + 1 * (size_t)HW + p0, x_a);
    load8(pb + 6 * (size_t)HW + p0, x_b);
    {
        Arr10 n6 = load_strip10(pb + 6*(size_t)HW + (rm ? p0 - WDIM : p0), lane, rm);
        Arr10 n1 = load_strip10(pb + 1*(size_t)HW + (rp ? p0 + WDIM : p0), lane, rp);
        own_ch(1, x_a, s_a);
        own_ch(6, x_b, s_b);
        vote(s_a, n6, 1, rm);
        vote(s_b, n1, 1, rp);
    }
    // ---- pair (2,5): d2 uses ch5@(i-1,j+1); d5 uses ch2@(i+1,j-1) ----
    load8(pb + 2 * (size_t)HW + p0, x_a);
    load8(pb + 5 * (size_t)HW + p0, x_b);
    {
        Arr10 n5 = load_strip10(pb + 5*(size_t)HW + (rm ? p0 - WDIM : p0), lane, rm);
        Arr10 n2 = load_strip10(pb + 2*(size_t)HW + (rp ? p0 + WDIM : p0), lane, rp);
        own_ch(2, x_a, s_a);
        own_ch(5, x_b, s_b);
        vote(s_a, n5, 2, rm);
        vote(s_b, n2, 0, rp);
    }
    // ---- pair (3,4): in-row; vote with shuffled SIGMOID VALUES ----
    load8(pb + 3 * (size_t)HW + p0, x_a);
    load8(pb + 4 * (size_t)HW + p0, x_b);
    {
        own_ch(3, x_a, s_a);
        own_ch(4, x_b, s_b);
        Arr10 v4 = strip10_from(s_b, lane);   // ch4 values, cols j0-1..j0+8
        Arr10 v3 = strip10_from(s_a, lane);   // ch3 values
#pragma unroll
        for (int k = 0; k < 8; ++k) {
            // boundary entries are 0 -> OOB vote contributes 0, no predicates
            fp[k] = fmaxf(fp[k], s_a[k] * v4.v[k]);      // d3: ch4@(i,j-1)
            fp[k] = fmaxf(fp[k], s_b[k] * v3.v[k + 2]);  // d4: ch3@(i,j+1)
        }
    }

    // ---------- epilogue: edge loss + dice partials ----------
    float e_num = 0.f, e_den = 0.f, inter = 0.f, fpsum = 0.f, tsum = 0.f;
#pragma unroll
    for (int k = 0; k < 8; ++k) {
        const float ef = (mb[k] & 256) ? 1.f : 0.f;
        const float m  = xmin[k];
        float sp;
        const float pmin = sig_sp(m, sp);           // sigmoid monotone
        e_num += ef * fminf(fmaxf(m, 0.f) + sp, 100.f);  // softplus(xmin)
        e_den += ef * pmin;
        inter += fp[k] * tk[k];
        fpsum += fp[k];
        tsum  += tk[k];
    }

    // ---------- block reduction of 6 partials ----------
    float vals[6] = {bce, e_num, e_den, inter, fpsum, tsum};
    __shared__ float red[4][6];
#pragma unroll
    for (int k = 0; k < 6; ++k) {
        float v = vals[k];
#pragma unroll
        for (int o = 32; o > 0; o >>= 1) v += __shfl_down(v, o, 64);
        if (lane == 0) red[wv][k] = v;
    }
    __syncthreads();
    if (tid < 6) {
        const int k = tid;
        const float sum = red[0][k] + red[1][k] + red[2][k] + red[3][k];
        if (mode == 1) {
            partials[k * NBLK + b * NBLKX + blockIdx.x] = sum;
        } else {
            double* dst;
            switch (k) {
                case 0:  dst = wsd + 0;       break;
                case 1:  dst = wsd + 1;       break;
                case 2:  dst = wsd + 2;       break;
                case 3:  dst = wsd + 3 + b;   break;
                case 4:  dst = wsd + 11 + b;  break;
                default: dst = wsd + 19 + b;  break;
            }
            atomicAdd(dst, (double)sum);
        }
    }
}

__global__ __launch_bounds__(256) void connect_loss_final(
        const float* __restrict__ partials,
        const double* __restrict__ wsd,
        float* __restrict__ out, int mode)
{
    __shared__ double red4[4];
    __shared__ double gsum[3];
    __shared__ double bsum[3][BATCH];
    const int t = threadIdx.x;

    if (mode == 1) {
        const int lane = t & 63, wid = t >> 6;
        {   // per-batch categories (k=3,4,5): 8 groups of 32 lanes
            const int g = t >> 5, e = t & 31;
#pragma unroll
            for (int k = 3; k < 6; ++k) {
                double v = 0.0;
                for (int m = e; m < NBLKX; m += 32)
                    v += (double)partials[k * NBLK + g * NBLKX + m];
                for (int o = 16; o > 0; o >>= 1) v += __shfl_down(v, o, 32);
                if (e == 0) bsum[k - 3][g] = v;
            }
        }
        for (int k = 0; k < 3; ++k) {   // global categories
            double v = 0.0;
            for (int idx = t; idx < NBLK; idx += 256)
                v += (double)partials[k * NBLK + idx];
            for (int o = 32; o > 0; o >>= 1) v += __shfl_down(v, o, 64);
            if (lane == 0) red4[wid] = v;
            __syncthreads();
            if (t == 0) gsum[k] = red4[0] + red4[1] + red4[2] + red4[3];
            __syncthreads();
        }
        if (t == 0) {
            const double conn_loss = gsum[0] / (double)((size_t)BATCH * 8 * HW);
            const double edge_loss = gsum[1] / gsum[2];
            double seg = 0.0;
            for (int bb = 0; bb < BATCH; ++bb) {
                const double dice = (2.0 * bsum[0][bb] + 1.0)
                                  / (bsum[1][bb] + bsum[2][bb] + 1.0);
                seg += 1.0 - dice;
            }
            out[0] = (float)(conn_loss + edge_loss + seg / (double)BATCH);
        }
    } else if (t == 0) {
        const double conn_loss = wsd[0] / (double)((size_t)BATCH * 8 * HW);
        const double edge_loss = wsd[1] / wsd[2];
        double seg = 0.0;
        for (int bb = 0; bb < BATCH; ++bb) {
            const double dice = (2.0 * wsd[3 + bb] + 1.0)
                              / (wsd[11 + bb] + wsd[19 + bb] + 1.0);
            seg += 1.0 - dice;
        }
        out[0] = (float)(conn_loss + edge_loss + seg / (double)BATCH);
    }
}

extern "C" void kernel_launch(void* const* d_in, const int* in_sizes, int n_in,
                              void* d_out, int out_size, void* d_ws, size_t ws_size,
                              hipStream_t stream)
{
    const float* pred = (const float*)d_in[0];   // (8, 8, 512, 512)
    const float* tgt  = (const float*)d_in[1];   // (8, 1, 512, 512)
    // d_in[2]/d_in[3] (hori/verti) are exact one-pixel shift permutation
    // matrices -> implemented as index shifts (verified rounds 1-4, absmax 0).

    const dim3 grid(NBLKX, BATCH);
    const size_t needA = (size_t)6 * NBLK * sizeof(float);

    if (ws_size >= needA) {
        float* partials = (float*)d_ws;
        connect_loss_main<<<grid, 256, 0, stream>>>(pred, tgt, partials, nullptr, 1);
        connect_loss_final<<<1, 256, 0, stream>>>(partials, nullptr, (float*)d_out, 1);
    } else {
        double* wsd = (double*)d_ws;
        hipMemsetAsync(d_ws, 0, 27 * sizeof(double), stream);
        connect_loss_main<<<grid, 256, 0, stream>>>(pred, tgt, nullptr, wsd, 0);
        connect_loss_final<<<1, 1, 0, stream>>>(nullptr, wsd, (float*)d_out, 0);
    }
}